// Round 13
// baseline (3478.518 us; speedup 1.0000x reference)
//
#include <hip/hip_runtime.h>
#include <hip/hip_bf16.h>

#define B_   256
#define T_   512
#define D_   64
#define H_   1024
#define NG   4096   // 4*H
#define KTOT 1088   // D + H
#define WPAD 1096   // +8 bf16 pad

typedef __attribute__((ext_vector_type(8)))  short short8;
typedef __attribute__((ext_vector_type(4)))  float f32x4;
typedef __attribute__((ext_vector_type(16))) float f32x16;

static __device__ __forceinline__ float tanh_clamped(float u) {
  u = fminf(fmaxf(u, -15.0f), 15.0f);
  float e = __expf(-2.0f * u);
  return (1.0f - e) / (1.0f + e);
}
static __device__ __forceinline__ unsigned short f2bf(float f) {
  union { float f; unsigned int u; } v; v.f = f;
  unsigned int r = (v.u + 0x7FFFu + ((v.u >> 16) & 1u)) >> 16; // RNE
  return (unsigned short)r;
}

// quad-perm DPP: lane i reads lane (i^X) within its 4-lane group. Pure VALU.
template <int CTRL>
static __device__ __forceinline__ float qperm(float v) {
  union { float f; int i; } a, b;
  a.f = v;
  b.i = __builtin_amdgcn_update_dpp(0, a.i, CTRL, 0xF, 0xF, true);
  return b.f;
}

__global__ void k_zero_flags(int* flags) {
  int gid = blockIdx.x * 256 + threadIdx.x;
  if (gid < 4096) flags[gid] = 0;
}

// Pack [Wx; Wh] -> Wp[n][k] bf16, n gate-interleaved: n = 4*j + gate, orig col = gate*1024 + j
__global__ void k_pack_w(const float* __restrict__ Wx, const float* __restrict__ Wh,
                         unsigned short* __restrict__ Wp) {
  __shared__ float tile[64][65];
  int nt = blockIdx.x & 63;   // 64 n-tiles
  int kt = blockIdx.x >> 6;   // 17 k-tiles
  int tx = threadIdx.x & 63, ty = threadIdx.x >> 6;
#pragma unroll
  for (int i = 0; i < 16; ++i) {
    int kl = i * 4 + ty;
    int k  = kt * 64 + kl;
    int n  = nt * 64 + tx;
    int oc = ((n & 3) << 10) | (n >> 2);
    float v = (k < D_) ? Wx[k * NG + oc] : Wh[(k - D_) * NG + oc];
    tile[kl][tx] = v;
  }
  __syncthreads();
#pragma unroll
  for (int i = 0; i < 16; ++i) {
    int nl = i * 4 + ty;
    int kl = tx;
    Wp[(size_t)(nt * 64 + nl) * KTOT + kt * 64 + kl] = f2bf(tile[kl][nl]);
  }
}

// Pack x (B,T,64) fp32 -> xbt[t][kk][b][8] bf16 (A-fragment friendly)
__global__ void k_pack_x(const float* __restrict__ x, unsigned short* __restrict__ xbt) {
  int gid = blockIdx.x * 256 + threadIdx.x;  // 1,048,576 chunks
  int b  = gid & 255;
  int kk = (gid >> 8) & 7;
  int t  = gid >> 11;
  const float* src = x + ((size_t)b * T_ + t) * 64 + kk * 8;
  short8 v;
#pragma unroll
  for (int i = 0; i < 8; ++i) v[i] = (short)f2bf(src[i]);
  *(short8*)(xbt + (size_t)gid * 8) = v;
}

__launch_bounds__(256, 1)
__global__ void k_scan(const unsigned short* __restrict__ Wp,
                       const unsigned short* __restrict__ xbt,
                       unsigned short* __restrict__ hbt,   // [2][128][256][8] bf16
                       float* __restrict__ hf,             // [256][1024] fp32 (t=511)
                       const float* __restrict__ bias,
                       int* __restrict__ flags) {
  __shared__ unsigned short Wl[64 * WPAD];       // 140,288 B
  __shared__ float exch[4][16][64];              //  16,384 B  (pairwise accS swap)
  __shared__ unsigned short hstage[4][32][8];    //   2,048 B  (per-wave h coalesce)
  __shared__ int wseq[4];                        //  pair handshake: data written
  __shared__ int rseq[4];                        //  pair handshake: data read
  const int tid  = threadIdx.x;
  const int bid  = blockIdx.x;
  // XCD-pair grouping: xcd = bid%8 (heuristic); m-group g on XCDs {2g,2g+1}
  const int m    = (bid >> 1) & 3;                   // m-group
  const int nt   = ((bid >> 3) << 1) | (bid & 1);    // index within group, 0..63
  const int n0   = nt * 64;
  const int wave = tid >> 6;
  const int lane = tid & 63;
  const int wr = wave >> 1, wc = wave & 1;

  if (tid < 4) { wseq[tid] = 0; rseq[tid] = 0; }
  // Stage this block's 64 W columns into LDS (once)
  for (int i = tid; i < 64 * (KTOT / 8); i += 256) {
    int c  = i / (KTOT / 8);
    int kk = i - c * (KTOT / 8);
    short8 v = *(const short8*)(Wp + (size_t)(n0 + c) * KTOT + kk * 8);
    *(short8*)((char*)Wl + c * (WPAD * 2) + kk * 16) = v;
  }
  __syncthreads();   // one-time: W staged, seq init

  const int khalf = lane >> 5;                 // 0/1: k-subblock of fragment
  const int rowA  = m * 64 + wr * 32 + (lane & 31);
  const int colB  = wc * 32 + (lane & 31);     // epilogue col (LDS-local)
  const int n     = n0 + colB;
  const int oc    = ((n & 3) << 10) | (n >> 2);
  const float bv  = bias[oc];
  const int s     = lane & 3;                  // gate: 0=i 1=f 2=g 3=o
  const int q     = (lane & 31) >> 2;          // jH sub-index for s==0 lanes
  const int jH    = n >> 2;
  // B-fragment bases: keep = own col-tile (wc), send = partner col-tile
  const char* WlK = (const char*)Wl + (size_t)(wc * 32 + (lane & 31)) * (WPAD * 2) + khalf * 16;
  const char* WlS = (const char*)Wl + (size_t)((1 - wc) * 32 + (lane & 31)) * (WPAD * 2) + khalf * 16;

  float c_state[16];
#pragma unroll
  for (int r = 0; r < 16; ++r) c_state[r] = 0.0f;

  // PER-PRODUCER-WAVE flags: dword (wr'*2 + wc') of the producer block's
  // 64B flag line. Consumer lane l's fragment j comes from exactly one
  // producer wave: block wc*32+j, wave (wr'=wr, wc'=l>>5) -> lane l polls
  // line (m*64 + wc*32 + (l&31)), dword (wr*2 + (l>>5)).
  int* flagline = flags + (m * 64 + nt) * 16;
  const unsigned int fo = (unsigned)(wr * 8 + wc * 4);   // own flag byte offset
  int* pollp = flags + (m * 64 + wc * 32 + (lane & 31)) * 16 + wr * 2 + khalf;

  const unsigned int voff0 = (unsigned)(khalf * 4096 + rowA * 16);  // bytes into h buffer
  const unsigned int vstore0 = (unsigned)(((nt * 2 + wc) * 256 + m * 64 + wr * 32) * 16);

  // x asm-load offsets (bytes) for the 4 fragments of one timestep
  unsigned int vx[4];
#pragma unroll
  for (int f = 0; f < 4; ++f) vx[f] = (unsigned)((f * 2 + khalf) * 4096 + rowA * 16);

  // prologue: issue x loads for t=0 (4 outstanding at loop entry)
  short8 ax[4];
  {
    const unsigned short* xb = xbt;  // t=0
#pragma unroll
    for (int f = 0; f < 4; ++f)
      asm volatile("global_load_dwordx4 %0, %1, %2"
                   : "=v"(ax[f]) : "v"(vx[f]), "s"(xb));
  }

  for (int t = 0; t < T_; ++t) {
    f32x16 accK;                                 // own col-tile: bias + x + h(k-half wc)
#pragma unroll
    for (int r = 0; r < 16; ++r) accK[r] = bv;

    // x fragments were issued in the previous step's publish tail
    asm volatile("s_waitcnt vmcnt(0)" ::: "memory");
    __builtin_amdgcn_sched_barrier(0);
#pragma unroll
    for (int kt = 0; kt < 4; ++kt) {
      short8 b8 = *(const short8*)(WlK + kt * 32);
      accK = __builtin_amdgcn_mfma_f32_32x32x16_bf16(ax[kt], b8, accK, 0, 0, 0);
    }

    if (t > 0) {
      __builtin_amdgcn_sched_barrier(0);
      for (;;) {
        int v = __hip_atomic_load(pollp, __ATOMIC_RELAXED, __HIP_MEMORY_SCOPE_AGENT);
        if (__all(v >= t)) break;
      }
      // bypass loads (sc0 sc1): read the coherence point (LLC); producers
      // stored write-through, so no cache-maintenance fences anywhere.
      const unsigned short* hsrc = hbt + (size_t)((t + 1) & 1) * 128 * 2048;

      // K-split: this wave loads ONLY k-range [wc*512, wc*512+512) -> 32
      // distinct fragments; A is reused for both col-tiles (accK, accS).
      short8 aH[32];
#pragma unroll
      for (int j = 0; j < 32; ++j) {
        unsigned int vo = voff0 + (unsigned)((wc * 32 + j) * 8192);
        asm volatile("global_load_dwordx4 %0, %1, %2 sc0 sc1"
                     : "=v"(aH[j]) : "v"(vo), "s"(hsrc));
      }
      f32x16 accS;                               // partner col-tile partial
#pragma unroll
      for (int r = 0; r < 16; ++r) accS[r] = 0.0f;

      // counted waits: MFMA group g starts once its 8 loads landed
#pragma unroll
      for (int g = 0; g < 4; ++g) {
        switch (g) {
          case 0: asm volatile("s_waitcnt vmcnt(24)" ::: "memory"); break;
          case 1: asm volatile("s_waitcnt vmcnt(16)" ::: "memory"); break;
          case 2: asm volatile("s_waitcnt vmcnt(8)"  ::: "memory"); break;
          case 3: asm volatile("s_waitcnt vmcnt(0)"  ::: "memory"); break;
        }
        __builtin_amdgcn_sched_barrier(0);
#pragma unroll
        for (int jj = 0; jj < 8; ++jj) {
          int j  = g * 8 + jj;
          int kt = wc * 32 + j;
          short8 bk = *(const short8*)(WlK + 128 + kt * 32);
          short8 bs = *(const short8*)(WlS + 128 + kt * 32);
          accK = __builtin_amdgcn_mfma_f32_32x32x16_bf16(aH[j], bk, accK, 0, 0, 0);
          accS = __builtin_amdgcn_mfma_f32_32x32x16_bf16(aH[j], bs, accS, 0, 0, 0);
        }
      }

      // pairwise accS swap with wave^1 via LDS handshake (NO block barrier):
      //   guard: partner consumed my step t-1 data (exch reuse safe)
      for (;;) {
        int v = __hip_atomic_load(&rseq[wave ^ 1], __ATOMIC_RELAXED, __HIP_MEMORY_SCOPE_WORKGROUP);
        if (v >= t - 1) break;
      }
      asm volatile("" ::: "memory");
#pragma unroll
      for (int r = 0; r < 16; ++r) exch[wave][r][lane] = accS[r];
      asm volatile("s_waitcnt lgkmcnt(0)" ::: "memory");   // exch visible
      __hip_atomic_store(&wseq[wave], t, __ATOMIC_RELAXED, __HIP_MEMORY_SCOPE_WORKGROUP);
      for (;;) {
        int v = __hip_atomic_load(&wseq[wave ^ 1], __ATOMIC_RELAXED, __HIP_MEMORY_SCOPE_WORKGROUP);
        if (v >= t) break;
      }
      asm volatile("" ::: "memory");
#pragma unroll
      for (int r = 0; r < 16; ++r) accK[r] += exch[wave ^ 1][r][lane];
      asm volatile("s_waitcnt lgkmcnt(0)" ::: "memory");   // reads retired
      __hip_atomic_store(&rseq[wave], t, __ATOMIC_RELAXED, __HIP_MEMORY_SCOPE_WORKGROUP);
    }

    // gates + state update; lanes 4j..4j+3 hold i,f,g,o of (row, j)
#pragma unroll
    for (int r = 0; r < 16; ++r) {
      float z  = accK[r];
      float u  = (s == 2) ? z : 0.5f * z;
      float tv = tanh_clamped(u);
      float av = (s == 2) ? tv : 0.5f * (1.0f + tv);
      float x1 = qperm<0xB1>(av);   // lane ^ 1
      float x2 = qperm<0x4E>(av);   // lane ^ 2
      float x3 = qperm<0x1B>(av);   // lane ^ 3
      float i_ = (s == 0) ? av : (s == 1) ? x1 : (s == 2) ? x2 : x3;
      float f_ = (s == 1) ? av : (s == 0) ? x1 : (s == 3) ? x2 : x3;
      float g_ = (s == 2) ? av : (s == 3) ? x1 : (s == 0) ? x2 : x3;
      float o_ = (s == 3) ? av : (s == 2) ? x1 : (s == 1) ? x2 : x3;
      float cn = f_ * c_state[r] + i_ * g_;
      c_state[r] = cn;
      float hn = o_ * tanh_clamped(cn);
      if (s == 0) {
        int rloc = 4 * khalf + (r & 3) + 8 * (r >> 2);   // 0..31 within wave
        if (t < T_ - 1) {
          hstage[wave][rloc][q] = f2bf(hn);   // private per-wave region
        } else {
          hf[(size_t)(m * 64 + wr * 32 + rloc) * H_ + jH] = hn;
        }
      }
    }

    if (t < T_ - 1) {
      // PER-WAVE publish: store own 512B region (write-through), prefetch x,
      // drain own store, then publish OWN per-wave flag immediately.
      asm volatile("s_waitcnt lgkmcnt(0)" ::: "memory");
      unsigned short* hdst = hbt + (size_t)(t & 1) * 128 * 2048;
      if (lane < 32) {
        f32x4 v = *(const f32x4*)&hstage[wave][lane][0];
        unsigned int vo = vstore0 + (unsigned)(lane * 16);
        asm volatile("global_store_dwordx4 %0, %1, %2 sc0 sc1"
                     :: "v"(vo), "v"(v), "s"(hdst) : "memory");
      }
      {
        const unsigned short* xb = xbt + (size_t)(t + 1) * 16384;
#pragma unroll
        for (int f = 0; f < 4; ++f)
          asm volatile("global_load_dwordx4 %0, %1, %2"
                       : "=v"(ax[f]) : "v"(vx[f]), "s"(xb));
      }
      asm volatile("s_waitcnt vmcnt(4)" ::: "memory");  // h-store done; x in flight
      if (lane == 0) {
        unsigned int fv = (unsigned)(t + 1);
        asm volatile("global_store_dword %0, %1, %2 sc0 sc1"
                     :: "v"(fo), "v"(fv), "s"(flagline) : "memory");
      }
    }
  }
}

__global__ void k_head(const float* __restrict__ hf, const float* __restrict__ Wr,
                       const float* __restrict__ br, float* __restrict__ out) {
  int bf = blockIdx.x;            // b*8 + f
  int b = bf >> 3, f = bf & 7;
  int lane = threadIdx.x;
  float s0 = 0.f, s1 = 0.f, s2 = 0.f;
  for (int j = lane; j < H_; j += 64) {
    float h = hf[(size_t)b * H_ + j];
    const float* w = Wr + ((size_t)f * H_ + j) * 3;
    s0 = fmaf(h, w[0], s0); s1 = fmaf(h, w[1], s1); s2 = fmaf(h, w[2], s2);
  }
#pragma unroll
  for (int o = 32; o >= 1; o >>= 1) {
    s0 += __shfl_xor(s0, o); s1 += __shfl_xor(s1, o); s2 += __shfl_xor(s2, o);
  }
  if (lane == 0) {
    out[bf * 3 + 0] = s0 + br[f * 3 + 0];
    out[bf * 3 + 1] = s1 + br[f * 3 + 1];
    out[bf * 3 + 2] = s2 + br[f * 3 + 2];
  }
}

extern "C" void kernel_launch(void* const* d_in, const int* in_sizes, int n_in,
                              void* d_out, int out_size, void* d_ws, size_t ws_size,
                              hipStream_t stream) {
  const float* x    = (const float*)d_in[0];
  const float* Wx   = (const float*)d_in[1];
  const float* Wh   = (const float*)d_in[2];
  const float* bias = (const float*)d_in[3];
  const float* Wr   = (const float*)d_in[4];
  const float* br   = (const float*)d_in[5];
  float* out = (float*)d_out;

  char* ws = (char*)d_ws;
  unsigned short* Wp  = (unsigned short*)ws;                        // 8,912,896 B
  unsigned short* xbt = (unsigned short*)(ws + 8912896);            // 16,777,216 B
  unsigned short* hbt = (unsigned short*)(ws + 8912896 + 16777216); // 1,048,576 B
  float* hf           = (float*)(ws + 8912896 + 16777216 + 1048576);// 1,048,576 B
  int* flags          = (int*)(ws + 8912896 + 16777216 + 1048576 + 1048576); // 16,384 B

  k_zero_flags<<<16, 256, 0, stream>>>(flags);
  k_pack_w<<<17 * 64, 256, 0, stream>>>(Wx, Wh, Wp);
  k_pack_x<<<4096, 256, 0, stream>>>(x, xbt);
  k_scan<<<256, 256, 0, stream>>>(Wp, xbt, hbt, hf, bias, flags);
  k_head<<<2048, 64, 0, stream>>>(hf, Wr, br, out);
}

// Round 14
// 3221.807 us; speedup vs baseline: 1.0797x; 1.0797x over previous
//
#include <hip/hip_runtime.h>
#include <hip/hip_bf16.h>

#define B_   256
#define T_   512
#define D_   64
#define H_   1024
#define NG   4096   // 4*H
#define KTOT 1088   // D + H
#define WPAD 1096   // +8 bf16 pad

typedef __attribute__((ext_vector_type(8)))  short short8;
typedef __attribute__((ext_vector_type(4)))  float f32x4;
typedef __attribute__((ext_vector_type(16))) float f32x16;

static __device__ __forceinline__ float tanh_clamped(float u) {
  u = fminf(fmaxf(u, -15.0f), 15.0f);
  float e = __expf(-2.0f * u);
  return (1.0f - e) / (1.0f + e);
}
static __device__ __forceinline__ unsigned short f2bf(float f) {
  union { float f; unsigned int u; } v; v.f = f;
  unsigned int r = (v.u + 0x7FFFu + ((v.u >> 16) & 1u)) >> 16; // RNE
  return (unsigned short)r;
}

// quad-perm DPP: lane i reads lane (i^X) within its 4-lane group. Pure VALU.
template <int CTRL>
static __device__ __forceinline__ float qperm(float v) {
  union { float f; int i; } a, b;
  a.f = v;
  b.i = __builtin_amdgcn_update_dpp(0, a.i, CTRL, 0xF, 0xF, true);
  return b.f;
}

__global__ void k_zero_flags(int* flags) {
  int gid = blockIdx.x * 256 + threadIdx.x;
  if (gid < 4096) flags[gid] = 0;
}

// Pack [Wx; Wh] -> Wp[n][k] bf16, n gate-interleaved: n = 4*j + gate, orig col = gate*1024 + j
__global__ void k_pack_w(const float* __restrict__ Wx, const float* __restrict__ Wh,
                         unsigned short* __restrict__ Wp) {
  __shared__ float tile[64][65];
  int nt = blockIdx.x & 63;   // 64 n-tiles
  int kt = blockIdx.x >> 6;   // 17 k-tiles
  int tx = threadIdx.x & 63, ty = threadIdx.x >> 6;
#pragma unroll
  for (int i = 0; i < 16; ++i) {
    int kl = i * 4 + ty;
    int k  = kt * 64 + kl;
    int n  = nt * 64 + tx;
    int oc = ((n & 3) << 10) | (n >> 2);
    float v = (k < D_) ? Wx[k * NG + oc] : Wh[(k - D_) * NG + oc];
    tile[kl][tx] = v;
  }
  __syncthreads();
#pragma unroll
  for (int i = 0; i < 16; ++i) {
    int nl = i * 4 + ty;
    int kl = tx;
    Wp[(size_t)(nt * 64 + nl) * KTOT + kt * 64 + kl] = f2bf(tile[kl][nl]);
  }
}

// Pack x (B,T,64) fp32 -> xbt[t][kk][b][8] bf16 (A-fragment friendly)
__global__ void k_pack_x(const float* __restrict__ x, unsigned short* __restrict__ xbt) {
  int gid = blockIdx.x * 256 + threadIdx.x;  // 1,048,576 chunks
  int b  = gid & 255;
  int kk = (gid >> 8) & 7;
  int t  = gid >> 11;
  const float* src = x + ((size_t)b * T_ + t) * 64 + kk * 8;
  short8 v;
#pragma unroll
  for (int i = 0; i < 8; ++i) v[i] = (short)f2bf(src[i]);
  *(short8*)(xbt + (size_t)gid * 8) = v;
}

__launch_bounds__(256, 1)
__global__ void k_scan(const unsigned short* __restrict__ Wp,
                       const unsigned short* __restrict__ xbt,
                       unsigned short* __restrict__ hbt,   // [2][128][256][8] bf16
                       float* __restrict__ hf,             // [256][1024] fp32 (t=511)
                       const float* __restrict__ bias,
                       int* __restrict__ flags) {
  __shared__ unsigned short Wl[64 * WPAD];       // 140,288 B
  __shared__ float exch[4][16][64];              //  16,384 B  (pairwise accS swap)
  __shared__ unsigned short hstage[4][32][8];    //   2,048 B  (per-wave h coalesce)
  __shared__ int wseq[4];                        //  pair handshake: data written
  __shared__ int rseq[4];                        //  pair handshake: data read
  __shared__ int pcnt[2];                        //  per-wr-pair publish counter
  const int tid  = threadIdx.x;
  const int bid  = blockIdx.x;
  // XCD-pair grouping: xcd = bid%8 (heuristic); m-group g on XCDs {2g,2g+1}
  const int m    = (bid >> 1) & 3;                   // m-group
  const int nt   = ((bid >> 3) << 1) | (bid & 1);    // index within group, 0..63
  const int n0   = nt * 64;
  const int wave = tid >> 6;
  const int lane = tid & 63;
  const int wr = wave >> 1, wc = wave & 1;

  if (tid < 4) { wseq[tid] = 0; rseq[tid] = 0; }
  if (tid < 2) pcnt[tid] = 0;
  // Stage this block's 64 W columns into LDS (once)
  for (int i = tid; i < 64 * (KTOT / 8); i += 256) {
    int c  = i / (KTOT / 8);
    int kk = i - c * (KTOT / 8);
    short8 v = *(const short8*)(Wp + (size_t)(n0 + c) * KTOT + kk * 8);
    *(short8*)((char*)Wl + c * (WPAD * 2) + kk * 16) = v;
  }
  __syncthreads();   // one-time: W staged, seq/cnt initialized

  const int khalf = lane >> 5;                 // 0/1: k-subblock of fragment
  const int rowA  = m * 64 + wr * 32 + (lane & 31);
  const int colB  = wc * 32 + (lane & 31);     // epilogue col (LDS-local)
  const int n     = n0 + colB;
  const int oc    = ((n & 3) << 10) | (n >> 2);
  const float bv  = bias[oc];
  const int s     = lane & 3;                  // gate: 0=i 1=f 2=g 3=o
  const int q     = (lane & 31) >> 2;          // jH sub-index for s==0 lanes
  const int jH    = n >> 2;
  // B-fragment bases: keep = own col-tile (wc), send = partner col-tile
  const char* WlK = (const char*)Wl + (size_t)(wc * 32 + (lane & 31)) * (WPAD * 2) + khalf * 16;
  const char* WlS = (const char*)Wl + (size_t)((1 - wc) * 32 + (lane & 31)) * (WPAD * 2) + khalf * 16;

  float c_state[16];
#pragma unroll
  for (int r = 0; r < 16; ++r) c_state[r] = 0.0f;

  // per-wr-half flags (dword wr*4 of the block's 64B flag line). Consumer
  // wave (wr,wc) depends ONLY on producers nt' in [wc*32,+32), half wr:
  // the wr=0 and wr=1 "planes" of each m-group are fully independent.
  // flagline is BLOCK-UNIFORM (legal "s" operand); wr-half goes in voffset.
  int* flagline = flags + (m * 64 + nt) * 16;
  const unsigned int fo = (unsigned)(wr * 16);   // byte offset of wr-half dword
  int* pollp  = flags + (m * 64 + wc * 32 + (lane & 31)) * 16 + wr * 4;

  const unsigned int voff0 = (unsigned)(khalf * 4096 + rowA * 16);  // bytes into h buffer
  const unsigned int vstore0 = (unsigned)(((nt * 2 + wc) * 256 + m * 64 + wr * 32) * 16);

  // x asm-load offsets (bytes) for the 4 fragments of one timestep
  unsigned int vx[4];
#pragma unroll
  for (int f = 0; f < 4; ++f) vx[f] = (unsigned)((f * 2 + khalf) * 4096 + rowA * 16);

  // prologue: issue x loads for t=0 (4 outstanding at loop entry)
  short8 ax[4];
  {
    const unsigned short* xb = xbt;  // t=0
#pragma unroll
    for (int f = 0; f < 4; ++f)
      asm volatile("global_load_dwordx4 %0, %1, %2"
                   : "=v"(ax[f]) : "v"(vx[f]), "s"(xb));
  }

  for (int t = 0; t < T_; ++t) {
    f32x16 accK;                                 // own col-tile: bias + x + h(k-half wc)
#pragma unroll
    for (int r = 0; r < 16; ++r) accK[r] = bv;

    // x fragments were issued in the previous step's publish tail
    asm volatile("s_waitcnt vmcnt(0)" ::: "memory");
    __builtin_amdgcn_sched_barrier(0);
#pragma unroll
    for (int kt = 0; kt < 4; ++kt) {
      short8 b8 = *(const short8*)(WlK + kt * 32);
      accK = __builtin_amdgcn_mfma_f32_32x32x16_bf16(ax[kt], b8, accK, 0, 0, 0);
    }

    if (t > 0) {
      __builtin_amdgcn_sched_barrier(0);
      for (;;) {
        int v = __hip_atomic_load(pollp, __ATOMIC_RELAXED, __HIP_MEMORY_SCOPE_AGENT);
        if (__all(v >= t)) break;
      }
      // bypass loads (sc0 sc1): read the coherence point (LLC); producers
      // stored write-through, so no cache-maintenance fences anywhere.
      const unsigned short* hsrc = hbt + (size_t)((t + 1) & 1) * 128 * 2048;

      // K-split: this wave loads ONLY k-range [wc*512, wc*512+512) -> 32
      // distinct fragments; A is reused for both col-tiles (accK, accS).
      short8 aH[32];
#pragma unroll
      for (int j = 0; j < 32; ++j) {
        unsigned int vo = voff0 + (unsigned)((wc * 32 + j) * 8192);
        asm volatile("global_load_dwordx4 %0, %1, %2 sc0 sc1"
                     : "=v"(aH[j]) : "v"(vo), "s"(hsrc));
      }
      f32x16 accS;                               // partner col-tile partial
#pragma unroll
      for (int r = 0; r < 16; ++r) accS[r] = 0.0f;

      // counted waits: MFMA group g starts once its 8 loads landed
#pragma unroll
      for (int g = 0; g < 4; ++g) {
        switch (g) {
          case 0: asm volatile("s_waitcnt vmcnt(24)" ::: "memory"); break;
          case 1: asm volatile("s_waitcnt vmcnt(16)" ::: "memory"); break;
          case 2: asm volatile("s_waitcnt vmcnt(8)"  ::: "memory"); break;
          case 3: asm volatile("s_waitcnt vmcnt(0)"  ::: "memory"); break;
        }
        __builtin_amdgcn_sched_barrier(0);
#pragma unroll
        for (int jj = 0; jj < 8; ++jj) {
          int j  = g * 8 + jj;
          int kt = wc * 32 + j;
          short8 bk = *(const short8*)(WlK + 128 + kt * 32);
          short8 bs = *(const short8*)(WlS + 128 + kt * 32);
          accK = __builtin_amdgcn_mfma_f32_32x32x16_bf16(aH[j], bk, accK, 0, 0, 0);
          accS = __builtin_amdgcn_mfma_f32_32x32x16_bf16(aH[j], bs, accS, 0, 0, 0);
        }
      }

      // pairwise accS swap with wave^1 via LDS handshake (NO block barrier):
      //   guard: partner consumed my step t-1 data (exch reuse safe)
      for (;;) {
        int v = __hip_atomic_load(&rseq[wave ^ 1], __ATOMIC_RELAXED, __HIP_MEMORY_SCOPE_WORKGROUP);
        if (v >= t - 1) break;
      }
      asm volatile("" ::: "memory");
#pragma unroll
      for (int r = 0; r < 16; ++r) exch[wave][r][lane] = accS[r];
      asm volatile("s_waitcnt lgkmcnt(0)" ::: "memory");   // exch visible
      __hip_atomic_store(&wseq[wave], t, __ATOMIC_RELAXED, __HIP_MEMORY_SCOPE_WORKGROUP);
      for (;;) {
        int v = __hip_atomic_load(&wseq[wave ^ 1], __ATOMIC_RELAXED, __HIP_MEMORY_SCOPE_WORKGROUP);
        if (v >= t) break;
      }
      asm volatile("" ::: "memory");
#pragma unroll
      for (int r = 0; r < 16; ++r) accK[r] += exch[wave ^ 1][r][lane];
      asm volatile("s_waitcnt lgkmcnt(0)" ::: "memory");   // reads retired
      __hip_atomic_store(&rseq[wave], t, __ATOMIC_RELAXED, __HIP_MEMORY_SCOPE_WORKGROUP);
    }

    // gates + state update; lanes 4j..4j+3 hold i,f,g,o of (row, j)
#pragma unroll
    for (int r = 0; r < 16; ++r) {
      float z  = accK[r];
      float u  = (s == 2) ? z : 0.5f * z;
      float tv = tanh_clamped(u);
      float av = (s == 2) ? tv : 0.5f * (1.0f + tv);
      float x1 = qperm<0xB1>(av);   // lane ^ 1
      float x2 = qperm<0x4E>(av);   // lane ^ 2
      float x3 = qperm<0x1B>(av);   // lane ^ 3
      float i_ = (s == 0) ? av : (s == 1) ? x1 : (s == 2) ? x2 : x3;
      float f_ = (s == 1) ? av : (s == 0) ? x1 : (s == 3) ? x2 : x3;
      float g_ = (s == 2) ? av : (s == 3) ? x1 : (s == 0) ? x2 : x3;
      float o_ = (s == 3) ? av : (s == 2) ? x1 : (s == 1) ? x2 : x3;
      float cn = f_ * c_state[r] + i_ * g_;
      c_state[r] = cn;
      float hn = o_ * tanh_clamped(cn);
      if (s == 0) {
        int rloc = 4 * khalf + (r & 3) + 8 * (r >> 2);   // 0..31 within wave
        if (t < T_ - 1) {
          hstage[wave][rloc][q] = f2bf(hn);   // private per-wave region
        } else {
          hf[(size_t)(m * 64 + wr * 32 + rloc) * H_ + jH] = hn;
        }
      }
    }

    if (t < T_ - 1) {
      // PER-WAVE publish: store own 512B region (write-through), prefetch x,
      // drain own store, then per-PAIR counter; 2nd wave of the pair stores
      // the wr-half flag (uniform base + wr*16 voffset).
      asm volatile("s_waitcnt lgkmcnt(0)" ::: "memory");
      unsigned short* hdst = hbt + (size_t)(t & 1) * 128 * 2048;
      if (lane < 32) {
        f32x4 v = *(const f32x4*)&hstage[wave][lane][0];
        unsigned int vo = vstore0 + (unsigned)(lane * 16);
        asm volatile("global_store_dwordx4 %0, %1, %2 sc0 sc1"
                     :: "v"(vo), "v"(v), "s"(hdst) : "memory");
      }
      {
        const unsigned short* xb = xbt + (size_t)(t + 1) * 16384;
#pragma unroll
        for (int f = 0; f < 4; ++f)
          asm volatile("global_load_dwordx4 %0, %1, %2"
                       : "=v"(ax[f]) : "v"(vx[f]), "s"(xb));
      }
      asm volatile("s_waitcnt vmcnt(4)" ::: "memory");  // h-store done; x in flight
      if (lane == 0) {
        int old = __hip_atomic_fetch_add(&pcnt[wr], 1, __ATOMIC_RELAXED,
                                         __HIP_MEMORY_SCOPE_WORKGROUP);
        if (old == 2 * t + 1) {
          unsigned int fv = (unsigned)(t + 1);
          asm volatile("global_store_dword %0, %1, %2 sc0 sc1"
                       :: "v"(fo), "v"(fv), "s"(flagline) : "memory");
        }
      }
    }
  }
}

__global__ void k_head(const float* __restrict__ hf, const float* __restrict__ Wr,
                       const float* __restrict__ br, float* __restrict__ out) {
  int bf = blockIdx.x;            // b*8 + f
  int b = bf >> 3, f = bf & 7;
  int lane = threadIdx.x;
  float s0 = 0.f, s1 = 0.f, s2 = 0.f;
  for (int j = lane; j < H_; j += 64) {
    float h = hf[(size_t)b * H_ + j];
    const float* w = Wr + ((size_t)f * H_ + j) * 3;
    s0 = fmaf(h, w[0], s0); s1 = fmaf(h, w[1], s1); s2 = fmaf(h, w[2], s2);
  }
#pragma unroll
  for (int o = 32; o >= 1; o >>= 1) {
    s0 += __shfl_xor(s0, o); s1 += __shfl_xor(s1, o); s2 += __shfl_xor(s2, o);
  }
  if (lane == 0) {
    out[bf * 3 + 0] = s0 + br[f * 3 + 0];
    out[bf * 3 + 1] = s1 + br[f * 3 + 1];
    out[bf * 3 + 2] = s2 + br[f * 3 + 2];
  }
}

extern "C" void kernel_launch(void* const* d_in, const int* in_sizes, int n_in,
                              void* d_out, int out_size, void* d_ws, size_t ws_size,
                              hipStream_t stream) {
  const float* x    = (const float*)d_in[0];
  const float* Wx   = (const float*)d_in[1];
  const float* Wh   = (const float*)d_in[2];
  const float* bias = (const float*)d_in[3];
  const float* Wr   = (const float*)d_in[4];
  const float* br   = (const float*)d_in[5];
  float* out = (float*)d_out;

  char* ws = (char*)d_ws;
  unsigned short* Wp  = (unsigned short*)ws;                        // 8,912,896 B
  unsigned short* xbt = (unsigned short*)(ws + 8912896);            // 16,777,216 B
  unsigned short* hbt = (unsigned short*)(ws + 8912896 + 16777216); // 1,048,576 B
  float* hf           = (float*)(ws + 8912896 + 16777216 + 1048576);// 1,048,576 B
  int* flags          = (int*)(ws + 8912896 + 16777216 + 1048576 + 1048576); // 16,384 B

  k_zero_flags<<<16, 256, 0, stream>>>(flags);
  k_pack_w<<<17 * 64, 256, 0, stream>>>(Wx, Wh, Wp);
  k_pack_x<<<4096, 256, 0, stream>>>(x, xbt);
  k_scan<<<256, 256, 0, stream>>>(Wp, xbt, hbt, hf, bias, flags);
  k_head<<<2048, 64, 0, stream>>>(hf, Wr, br, out);
}